// Round 1
// baseline (106.032 us; speedup 1.0000x reference)
//
#include <hip/hip_runtime.h>

// CRF NLL: meet-in-the-middle VALU scan, fwd and bwd chains in SEPARATE
// WAVES of one block (2 waves/block, 128 blocks).
//   fwd (wave 0):  q'[j] = (sum_i q[i] Fm[i]) * exp(f_t[j]), t = 1..255
//                  (never masked: len >= 256 -> no select at all)
//   bwd (wave 1):  p[j] = exp(f_tau[j]) * g[j]; g'[i] = sum_j p[j] Bm[j],
//                  tau = 511..256, holds while tau >= len;
//                  g init = exp(trans[:,END])
//   meet: forward = C_f + C_b + log(sum_j q[j] * g[j])   (t-invariant)
//
// R15 changes vs R14 (43.6us dispatch):
//  1. BATCHED BROADCASTS: R14 interleaved v_readlane/v_fmac pairs; every
//     fmac ate the SGPR write-back hazard of its readlane (~36 x ~8cyc
//     ~= the measured 408cyc/step vs ~180cyc issue floor). Now all 34
//     readlanes issue back-to-back, sched_barrier(0) fences, then 34
//     fmacs run against long-ready SGPRs.
//  2. 34-term dot (exact): q[START]=0 / Fm[END][.]=0 fwd; Bm[.][START]=0 /
//     g[END]=0 bwd -> terms 34,35 contribute exactly 0 (exp(-1000)
//     underflows to 0.0f). Outputs for those lanes still computed
//     lane-parallel (free) and are exactly 0 where they must be.
//  3. Renorm folded OFF the serial chain: scale rcp(m) multiplies the
//     PREFETCHED emission of the next step instead of q itself
//     (mathematically the identical uniform scale; Cf/Cb bookkeeping
//     unchanged). Bwd uses a mask-aware fold: scale applied+logged only
//     when the next step is unmasked (holds keep g constant & bounded);
//     final cross-iteration fold guarded out (result invariant).
//  4. fwd restructured to exactly 255 steps (15 iters + 15-step tail),
//     no mask select anywhere on the fwd chain.
// R2/R3 lessons kept: named registers only, waves_per_eu(1,1), batched
// 8-deep double-buffered prefetch, exp off the serial chain.

namespace {
constexpr int kB = 128;
constexpr int kS = 512;
constexpr int kT = 36;
constexpr int kStart = 34;
constexpr int kEnd = 35;

__device__ __forceinline__ float readlane_f(float v, int lane) {
    return __builtin_bit_cast(float, __builtin_amdgcn_readlane(__builtin_bit_cast(int, v), lane));
}

__device__ __forceinline__ float wave_sum(float v) {
#pragma unroll
    for (int off = 32; off; off >>= 1) v += __shfl_xor(v, off, 64);
    return v;
}

__device__ __forceinline__ int wave_sum_i(int v) {
#pragma unroll
    for (int off = 32; off; off >>= 1) v += __shfl_xor(v, off, 64);
    return v;
}

// n = term index, a = accumulator index (rotates 0..3 to break fma chains)
#define FOR34(X) \
    X(0, 0) X(1, 1) X(2, 2) X(3, 3) X(4, 0) X(5, 1) X(6, 2) X(7, 3) \
    X(8, 0) X(9, 1) X(10, 2) X(11, 3) X(12, 0) X(13, 1) X(14, 2) X(15, 3) \
    X(16, 0) X(17, 1) X(18, 2) X(19, 3) X(20, 0) X(21, 1) X(22, 2) X(23, 3) \
    X(24, 0) X(25, 1) X(26, 2) X(27, 3) X(28, 0) X(29, 1) X(30, 2) X(31, 3) \
    X(32, 0) X(33, 1)

#define FMDECL(n, a) float Fm##n;
#define FMINIT(n, a) Fm##n = __expf(trans[(n)*kT + jc]);
#define BMDECL(n, a) float Bm##n;
#define BMINIT(n, a) Bm##n = __expf(trans[jc * kT + (n)]);
#define RLD(n, a) const float s##n = readlane_f(src, n);
#define FD(n, a) v##a = fmaf(s##n, Fm##n, v##a);
#define BD(n, a) w##a = fmaf(s##n, Bm##n, w##a);

// clamped row loads (values unused when out of range; addr in-bounds)
#define LDF(t) fl[(size_t)(((t) < kS - 1) ? (t) : (kS - 1)) * kT]
#define LDBW(t) fl[(size_t)(((t) > 0) ? (t) : 0) * kT]

__global__ __attribute__((amdgpu_flat_work_group_size(128, 128),
                          amdgpu_waves_per_eu(1, 1)))
void crf_split_kernel(const float* __restrict__ feats,   // (B,S,T)
                      const float* __restrict__ trans,   // (T,T)
                      const int* __restrict__ mask,      // (B,S)
                      const int* __restrict__ tags,      // (B,S)
                      float* __restrict__ out) {         // scalar
    const int b = blockIdx.x;
    const int tid = threadIdx.x;
    const int w = tid >> 6;                   // 0 = fwd wave, 1 = bwd wave
    const int j = tid & 63;                   // lane = state index
    const int jc = (j < kT) ? j : (kT - 1);   // clamped (addressing only)
    const float* fbase = feats + (size_t)b * kS * kT;
    const float* fl = fbase + jc;             // per-lane feats column
    const int* mb = mask + b * kS;
    const int* tb = tags + b * kS;

    __shared__ float gbuf[64];   // gamma from bwd wave
    __shared__ float cbbuf;      // C_b from bwd wave

    // ---- sequence length (contiguous-prefix mask); len in [256, 512] ----
    int len = 0;
#pragma unroll
    for (int k = 0; k < kS / 64; ++k) len += mb[k * 64 + j];
    len = wave_sum_i(len);

    float q = 0.f, Cf = 0.f;  // fwd results (live into the epilogue)

    if (w == 1) {
        // ================== backward wave: tau = 511..256 ==================
        FOR34(BMDECL)
        FOR34(BMINIT)
        float g = (j < kT) ? __expf(trans[j * kT + kEnd]) : 0.f;
        float Cb = 0.f;

        auto bstep = [&](float eb, int tau) {
            const float src = eb * g;
            float w0 = 0.f, w1 = 0.f, w2 = 0.f, w3 = 0.f;
            FOR34(RLD)
            __builtin_amdgcn_sched_barrier(0);
            FOR34(BD)
            const float ng = (w0 + w1) + (w2 + w3);
            g = (tau < len) ? ng : g;  // hold while masked
        };
        // mask-aware fold: uniform scale applied to the NEXT step's
        // prefetched emission (off the serial chain). Only applied+logged
        // when that step actually updates g (holds keep g constant & O(1)).
        auto renormB = [&](float& eb_next, int tau_next) {
            const float mg = readlane_f(g, 0);
            const float lg = __logf(mg);
            const float r = __builtin_amdgcn_rcpf(mg);
            if (tau_next < len) { Cb += lg; eb_next *= r; }
        };

        float pA0, pA1, pA2, pA3, pA4, pA5, pA6, pA7;
        float pB0, pB1, pB2, pB3, pB4, pB5, pB6, pB7;
        float eA0, eA1, eA2, eA3, eA4, eA5, eA6, eA7;
        pA0 = LDBW(511); pA1 = LDBW(510); pA2 = LDBW(509); pA3 = LDBW(508);
        pA4 = LDBW(507); pA5 = LDBW(506); pA6 = LDBW(505); pA7 = LDBW(504);
        eA0 = __expf(pA0); eA1 = __expf(pA1); eA2 = __expf(pA2); eA3 = __expf(pA3);
        eA4 = __expf(pA4); eA5 = __expf(pA5); eA6 = __expf(pA6); eA7 = __expf(pA7);

        int it0 = 0;
        while (it0 < kS / 2) {
            pB0 = LDBW(503 - it0); pB1 = LDBW(502 - it0); pB2 = LDBW(501 - it0); pB3 = LDBW(500 - it0);
            pB4 = LDBW(499 - it0); pB5 = LDBW(498 - it0); pB6 = LDBW(497 - it0); pB7 = LDBW(496 - it0);
            bstep(eA0, 511 - it0); bstep(eA1, 510 - it0);
            bstep(eA2, 509 - it0); bstep(eA3, 508 - it0);
            renormB(eA4, 507 - it0);
            bstep(eA4, 507 - it0); bstep(eA5, 506 - it0);
            bstep(eA6, 505 - it0); bstep(eA7, 504 - it0);
            eA0 = __expf(pB0); eA1 = __expf(pB1); eA2 = __expf(pB2); eA3 = __expf(pB3);
            eA4 = __expf(pB4); eA5 = __expf(pB5); eA6 = __expf(pB6); eA7 = __expf(pB7);
            renormB(eA0, 503 - it0);

            pA0 = LDBW(495 - it0); pA1 = LDBW(494 - it0); pA2 = LDBW(493 - it0); pA3 = LDBW(492 - it0);
            pA4 = LDBW(491 - it0); pA5 = LDBW(490 - it0); pA6 = LDBW(489 - it0); pA7 = LDBW(488 - it0);
            bstep(eA0, 503 - it0); bstep(eA1, 502 - it0);
            bstep(eA2, 501 - it0); bstep(eA3, 500 - it0);
            renormB(eA4, 499 - it0);
            bstep(eA4, 499 - it0); bstep(eA5, 498 - it0);
            bstep(eA6, 497 - it0); bstep(eA7, 496 - it0);
            eA0 = __expf(pA0); eA1 = __expf(pA1); eA2 = __expf(pA2); eA3 = __expf(pA3);
            eA4 = __expf(pA4); eA5 = __expf(pA5); eA6 = __expf(pA6); eA7 = __expf(pA7);
            // cross-iteration fold target only exists for non-final iters;
            // dropping the last renorm is exact (result invariant to it).
            if (it0 < kS / 2 - 16) renormB(eA0, 495 - it0);
            it0 += 16;
        }
        gbuf[j] = g;              // gamma_256 (lanes >= 36 and END: exactly 0)
        if (j == 0) cbbuf = Cb;
    } else {
        // ================== forward wave: t = 1..255 (never masked) =======
        FOR34(FMDECL)
        FOR34(FMINIT)
        const float a0 = (j < kT) ? (fl[0] + trans[kStart * kT + jc]) : -1e30f;
        Cf = readlane_f(a0, 0);
        q = __expf(a0 - Cf);

        auto fstep = [&](float ef) {
            const float src = q;
            float v0 = 0.f, v1 = 0.f, v2 = 0.f, v3 = 0.f;
            FOR34(RLD)
            __builtin_amdgcn_sched_barrier(0);
            FOR34(FD)
            q = ((v0 + v1) + (v2 + v3)) * ef;
        };
        auto renormF = [&](float& ef_next) {  // fold scale into prefetched emission
            const float mf = readlane_f(q, 0);
            Cf += __logf(mf);
            ef_next *= __builtin_amdgcn_rcpf(mf);
        };

        float pA0, pA1, pA2, pA3, pA4, pA5, pA6, pA7;
        float pB0, pB1, pB2, pB3, pB4, pB5, pB6, pB7;
        float eA0, eA1, eA2, eA3, eA4, eA5, eA6, eA7;
        pA0 = LDF(1); pA1 = LDF(2); pA2 = LDF(3); pA3 = LDF(4);
        pA4 = LDF(5); pA5 = LDF(6); pA6 = LDF(7); pA7 = LDF(8);
        eA0 = __expf(pA0); eA1 = __expf(pA1); eA2 = __expf(pA2); eA3 = __expf(pA3);
        eA4 = __expf(pA4); eA5 = __expf(pA5); eA6 = __expf(pA6); eA7 = __expf(pA7);

        int it0 = 0;
        while (it0 < 240) {  // 15 iters -> t = 1..240
            pB0 = LDF(it0 + 9);  pB1 = LDF(it0 + 10); pB2 = LDF(it0 + 11); pB3 = LDF(it0 + 12);
            pB4 = LDF(it0 + 13); pB5 = LDF(it0 + 14); pB6 = LDF(it0 + 15); pB7 = LDF(it0 + 16);
            fstep(eA0); fstep(eA1); fstep(eA2); fstep(eA3);
            renormF(eA4);
            fstep(eA4); fstep(eA5); fstep(eA6); fstep(eA7);
            eA0 = __expf(pB0); eA1 = __expf(pB1); eA2 = __expf(pB2); eA3 = __expf(pB3);
            eA4 = __expf(pB4); eA5 = __expf(pB5); eA6 = __expf(pB6); eA7 = __expf(pB7);
            renormF(eA0);

            pA0 = LDF(it0 + 17); pA1 = LDF(it0 + 18); pA2 = LDF(it0 + 19); pA3 = LDF(it0 + 20);
            pA4 = LDF(it0 + 21); pA5 = LDF(it0 + 22); pA6 = LDF(it0 + 23); pA7 = LDF(it0 + 24);
            fstep(eA0); fstep(eA1); fstep(eA2); fstep(eA3);
            renormF(eA4);
            fstep(eA4); fstep(eA5); fstep(eA6); fstep(eA7);
            eA0 = __expf(pA0); eA1 = __expf(pA1); eA2 = __expf(pA2); eA3 = __expf(pA3);
            eA4 = __expf(pA4); eA5 = __expf(pA5); eA6 = __expf(pA6); eA7 = __expf(pA7);
            renormF(eA0);  // folds into next iter's (or the tail's) first step
            it0 += 16;
        }
        // tail: t = 241..255 (eA holds e[241..248], fold already in eA0)
        float pT0 = LDF(249), pT1 = LDF(250), pT2 = LDF(251), pT3 = LDF(252);
        float pT4 = LDF(253), pT5 = LDF(254), pT6 = LDF(255);
        fstep(eA0); fstep(eA1); fstep(eA2); fstep(eA3);
        renormF(eA4);
        fstep(eA4); fstep(eA5); fstep(eA6); fstep(eA7);
        float eT0 = __expf(pT0), eT1 = __expf(pT1), eT2 = __expf(pT2), eT3 = __expf(pT3);
        float eT4 = __expf(pT4), eT5 = __expf(pT5), eT6 = __expf(pT6);
        renormF(eT0);
        fstep(eT0); fstep(eT1); fstep(eT2); fstep(eT3);
        renormF(eT4);
        fstep(eT4); fstep(eT5); fstep(eT6);
        // q left unrenormalized for <=3 steps: |q| <= e^~26, safe in f32.
    }

    __syncthreads();

    if (w == 0) {
        // ---- meet: Z = sum_j q[j] * gamma[j]; gamma is exactly 0 for
        //      START-unreachable / junk lanes, so the sum is exact ----
        const float Z = wave_sum(q * gbuf[j]);
        const float forward_b = Cf + cbbuf + __logf(Z);

        // ---- gold score (parallel over time steps) ----
        float gold = 0.f;
        for (int k = j; k < kS; k += 64) {
            if (k < len) {
                const int tg = tb[k];
                const int pv = (k == 0) ? kStart : tb[k - 1];
                gold += fbase[(size_t)k * kT + tg] + trans[pv * kT + tg];
            }
        }
        gold = wave_sum(gold);

        if (j == 0) {
            gold += trans[tb[len - 1] * kT + kEnd];
            atomicAdd(out, (forward_b - gold) * (1.0f / kB));
        }
    }
}

}  // namespace

extern "C" void kernel_launch(void* const* d_in, const int* in_sizes, int n_in,
                              void* d_out, int out_size, void* d_ws, size_t ws_size,
                              hipStream_t stream) {
    const float* feats = (const float*)d_in[0];
    const float* trans = (const float*)d_in[1];
    const int* mask = (const int*)d_in[2];
    const int* tags = (const int*)d_in[3];
    float* out = (float*)d_out;

    (void)hipMemsetAsync(out, 0, sizeof(float), stream);
    crf_split_kernel<<<dim3(kB), dim3(128), 0, stream>>>(feats, trans, mask, tags, out);
}